// Round 18
// baseline (393.281 us; speedup 1.0000x reference)
//
#include <hip/hip_runtime.h>

// ---------------------------------------------------------------------------
// SelfConsistNet r18 = r17 (best: 347us) + conv_s1 CO-SPLIT for concurrency:
//  - wave tile 32co x 64px (cot=16), grid 4096 single-wave blocks ->
//    16 blocks/CU = 4 waves/SIMD (was 2). Unlike r13 (px-split: doubled
//    per-CU A-issue) and r15 (K-split: combine overhead), co-split keeps
//    per-CU A-issue count INVARIANT and needs no epilogue.
//  - acc 32 VGPR -> fits launch_bounds(64,4) without the r13 VGPR squeeze.
//  - act buffer SINGLE-buffered granule-major [cg][101][8] (6.5KB; program
//    order makes it safe in a single wave) -> 103KB/CU at 16 blocks.
//  - remap: bid = (b%8) | cot<<3 | (b/8)<<7; XCD=b%8, co-residents share cot.
//  - conv1/gram/head unchanged from r17.
// ---------------------------------------------------------------------------

using short8 = __attribute__((ext_vector_type(8))) short;   // 8 bf16 (4 VGPR)
using f32x4  = __attribute__((ext_vector_type(4))) float;   // MFMA acc
typedef unsigned short u16;
typedef unsigned int   u32;

#define MFMA(a,b,c) __builtin_amdgcn_mfma_f32_16x16x32_bf16((a),(b),(c),0,0,0)

__device__ __forceinline__ u16 f2b(float f){
    u32 u = __builtin_bit_cast(u32, f);
    u += 0x7FFFu + ((u >> 16) & 1u);        // RNE
    return (u16)(u >> 16);
}
__device__ __forceinline__ float b2f(u16 h){
    u32 u = ((u32)h) << 16;
    return __builtin_bit_cast(float, u);
}
__device__ __forceinline__ u32 pack2(float a, float b){
    return (u32)f2b(a) | ((u32)f2b(b) << 16);
}
__device__ __forceinline__ float sigmoidf_(float v){
    return 1.0f / (1.0f + __expf(-v));
}

// ---------------------------------------------------------------------------
// Weight prep (unchanged): bf16 [dydx][cc][co][40] fragment tiles, BN folded.
// ---------------------------------------------------------------------------
__global__ __launch_bounds__(256)
void prep_kernel(const float* __restrict__ w1, const float* __restrict__ s1,
                 const float* __restrict__ w2, const float* __restrict__ s2,
                 const float* __restrict__ w3, const float* __restrict__ s3,
                 const float* __restrict__ w4, const float* __restrict__ s4,
                 const float* __restrict__ wd, const float* __restrict__ sd,
                 const float* __restrict__ ew,
                 u16* __restrict__ wp1, u16* __restrict__ wp2,
                 u16* __restrict__ wp3, u16* __restrict__ wp4,
                 u16* __restrict__ wpd, u16* __restrict__ wpe)
{
    const int N2 = 9*16*512*40, N1 = 9*8*512*40, ND = 8*512*40, NE = 8*128*40;
    int t = blockIdx.x * 256 + threadIdx.x;
    if (t < N2) {
        int j = t % 40; int r = t / 40; int co = r & 511; int q = r >> 9;
        int cc = q & 15; int dydx = q >> 4;
        float v = (j < 32) ? w2[(co*512 + cc*32 + j)*9 + dydx] * s2[co] : 0.f;
        wp2[t] = f2b(v); return;
    }
    t -= N2;
    if (t < N2) {
        int j = t % 40; int r = t / 40; int co = r & 511; int q = r >> 9;
        int cc = q & 15; int dydx = q >> 4;
        float v = (j < 32) ? w3[(co*512 + cc*32 + j)*9 + dydx] * s3[co] : 0.f;
        wp3[t] = f2b(v); return;
    }
    t -= N2;
    if (t < N2) {
        int j = t % 40; int r = t / 40; int co = r & 511; int q = r >> 9;
        int cc = q & 15; int dydx = q >> 4;
        float v = (j < 32) ? w4[(co*512 + cc*32 + j)*9 + dydx] * s4[co] : 0.f;
        wp4[t] = f2b(v); return;
    }
    t -= N2;
    if (t < N1) {
        int j = t % 40; int r = t / 40; int co = r & 511; int q = r >> 9;
        int cc = q & 7; int dydx = q >> 3;
        float v = (j < 32) ? w1[(co*256 + cc*32 + j)*9 + dydx] * s1[co] : 0.f;
        wp1[t] = f2b(v); return;
    }
    t -= N1;
    if (t < ND) {
        int j = t % 40; int r = t / 40; int co = r & 511; int cc = r >> 9;
        float v = (j < 32) ? wd[co*256 + cc*32 + j] * sd[co] : 0.f;
        wpd[t] = f2b(v); return;
    }
    t -= ND;
    if (t < NE) {
        int j = t % 40; int r = t / 40; int e = r & 127; int cc = r >> 7;
        float v = (j < 32) ? ew[e*256 + cc*32 + j] : 0.f;
        wpe[t] = f2b(v);
    }
}

// ---------------------------------------------------------------------------
// K1: conv3x3 s2 (r17: grid (bpair,cot), setprio).
// ---------------------------------------------------------------------------
__global__ __launch_bounds__(512, 2)
void conv1_kernel(const float* __restrict__ x, const u16* __restrict__ wp,
                  const float* __restrict__ bnb, u16* __restrict__ out)
{
    const int b0  = blockIdx.x * 2;      // batch pair (XCD = bid%8 = bp%8)
    const int cot = blockIdx.y;          // 0..1
    const int tid = threadIdx.x;
    const int wid = tid >> 6, lane = tid & 63;
    const int ln = lane & 15, kg = lane >> 4;
    const int wco = wid >> 1;            // 0..3
    const int bb  = wid & 1;             // 0..1

    __shared__ u16 actb[2][2*289*40];    // 92,480 B

    {
        short8 zz = {0,0,0,0,0,0,0,0};
        short8* ab = (short8*)&actb[0][0];
        for (int j = tid; j < 2*2*289*40/8; j += 512) ab[j] = zz;
    }
    __syncthreads();

    auto stage_act = [&](int cc, int p){
        #pragma unroll
        for (int it = 0; it < 16; ++it){
            int f = it*512 + tid;                    // 8192 dwords
            int bb2 = f >> 12; int rem = f & 4095;
            int cip = rem >> 8; int px = rem & 255;
            const float* src = &x[(((size_t)(b0+bb2)*256 + cc*32 + 2*cip)*256) + px];
            float v0 = src[0], v1 = src[256];
            int r = ((px >> 4) + 1)*17 + (px & 15) + 1;
            *(u32*)&actb[p][(bb2*289 + r)*40 + 2*cip] = pack2(v0, v1);
        }
    };

    stage_act(0, 0);
    __syncthreads();

    f32x4 zero4 = {0.f,0.f,0.f,0.f};
    f32x4 acc[4][4];
    #pragma unroll
    for (int mf = 0; mf < 4; ++mf)
        #pragma unroll
        for (int nf = 0; nf < 4; ++nf) acc[mf][nf] = zero4;

    int bbase[4];
    #pragma unroll
    for (int nf = 0; nf < 4; ++nf){
        int px = nf*16 + ln;
        bbase[nf] = (bb*289 + 34*(px>>3) + 2*(px&7))*40 + kg*8;
    }

    for (int cc = 0; cc < 8; ++cc){
        if (cc < 7) stage_act(cc+1, (cc+1) & 1);
        const u16* abp = actb[cc & 1];
        #pragma unroll
        for (int d = 0; d < 9; ++d){
            const u16* wdp = wp + ((size_t)(d*8 + cc)*512 + cot*256)*40;
            int dy = d/3, dx = d - dy*3;
            int shift = (dy*17 + dx)*40;
            short8 A[4];
            #pragma unroll
            for (int mf = 0; mf < 4; ++mf)
                A[mf] = *(const short8*)&wdp[(wco*64 + mf*16 + ln)*40 + kg*8];
            __builtin_amdgcn_s_setprio(1);
            #pragma unroll
            for (int nf = 0; nf < 4; ++nf){
                short8 B = *(const short8*)&abp[bbase[nf] + shift];
                #pragma unroll
                for (int mf = 0; mf < 4; ++mf)
                    acc[mf][nf] = MFMA(A[mf], B, acc[mf][nf]);
            }
            __builtin_amdgcn_s_setprio(0);
        }
        __syncthreads();
    }

    #pragma unroll
    for (int mf = 0; mf < 4; ++mf){
        int co0 = cot*256 + wco*64 + mf*16 + kg*4;
        float4 bv = *(const float4*)&bnb[co0];
        #pragma unroll
        for (int nf = 0; nf < 4; ++nf){
            int px = nf*16 + ln;
            size_t o = (((size_t)(b0+bb)*64) + px)*512 + co0;
            f32x4 a = acc[mf][nf];
            ushort4 st;
            st.x = f2b(fmaxf(a[0] + bv.x, 0.f));
            st.y = f2b(fmaxf(a[1] + bv.y, 0.f));
            st.z = f2b(fmaxf(a[2] + bv.z, 0.f));
            st.w = f2b(fmaxf(a[3] + bv.w, 0.f));
            *(ushort4*)&out[o] = st;
        }
    }
}

// ---------------------------------------------------------------------------
// K2/K3/K4 (r18): single-wave blocks, 32co x 64px. Grid 4096:
//   bid = (b%8) | cot<<3 | (b/8)<<7;  cot = (bid>>3)&15;
//   b = (bid&7) | ((bid>>7)<<3); XCD = b%8; co-residents (Δ256) share cot.
// Act LDS single-buffered granule-major [cg][101][8] (plane 808, 6464 B).
// A direct from global (6 frags per dy), setprio on MFMA clusters.
// ---------------------------------------------------------------------------
template<int DOWN, int RES>
__global__ __launch_bounds__(64, 4)
void conv_s1_kernel(const u16* __restrict__ in, const u16* __restrict__ wp,
                    const float* __restrict__ bnb,
                    const float* __restrict__ x, const u16* __restrict__ wpd,
                    const float* __restrict__ dbb,
                    const u16* __restrict__ res, u16* __restrict__ out)
{
    const int bid = blockIdx.x;          // 0..4095
    const int cot = (bid >> 3) & 15;     // 0..15 (32 co)
    const int b   = (bid & 7) | ((bid >> 7) << 3);   // 0..255; XCD = b%8
    const int lane = threadIdx.x;        // 0..63, single wave
    const int ln = lane & 15, kg = lane >> 4;

    __shared__ u16 actb[3232];           // [cg][101][8], plane 808; 6,464 B

    {
        short8 zz = {0,0,0,0,0,0,0,0};
        short8* ab = (short8*)&actb[0];
        #pragma unroll
        for (int it = 0; it < 7; ++it){
            int j = it*64 + lane;
            if (j < 404) ab[j] = zz;
        }
    }

    // staging: 256 short8 per cc-chunk, 4 per lane; dest [cg][row][8]
    int s_ld[4]; size_t s_go[4];
    #pragma unroll
    for (int it = 0; it < 4; ++it){
        int j = it*64 + lane;
        int px = j >> 2, cg = j & 3;
        int row = ((px>>3)+1)*10 + (px&7) + 1;       // interior 11..88
        s_ld[it] = cg*808 + row*8;
        s_go[it] = (((size_t)b*64 + px)*512) + cg*8;
    }

    short8 sreg[4];
    auto stage_load = [&](int cc){
        #pragma unroll
        for (int it = 0; it < 4; ++it)
            sreg[it] = *(const short8*)&in[s_go[it] + cc*32];
    };
    auto stage_store = [&](){
        #pragma unroll
        for (int it = 0; it < 4; ++it)
            *(short8*)&actb[s_ld[it]] = sreg[it];
    };

    stage_load(0); stage_store();

    f32x4 zero4 = {0.f,0.f,0.f,0.f};
    f32x4 acc[2][4];
    #pragma unroll
    for (int mf = 0; mf < 2; ++mf)
        #pragma unroll
        for (int nf = 0; nf < 4; ++nf) acc[mf][nf] = zero4;

    int bro[4];
    #pragma unroll
    for (int nf = 0; nf < 4; ++nf){
        int px = nf*16 + ln;
        bro[nf] = kg*808 + ((px>>3)*10 + (px&7))*8;
    }
    const int aoff = ln*40 + kg*8;
    const int abase = cot*32*40;

    for (int cc = 0; cc < 16; ++cc){
        if (cc < 15) stage_load(cc+1);
        #pragma unroll
        for (int dy = 0; dy < 3; ++dy){
            // preload all 6 A-fragments for this dy (3 dx x 2 mf)
            short8 A[3][2];
            #pragma unroll
            for (int dx = 0; dx < 3; ++dx){
                const u16* wdp = wp + (size_t)((dy*3+dx)*16 + cc)*512*40 + abase;
                #pragma unroll
                for (int mf = 0; mf < 2; ++mf)
                    A[dx][mf] = *(const short8*)&wdp[mf*640 + aoff];
            }
            __builtin_amdgcn_s_setprio(1);
            #pragma unroll
            for (int dx = 0; dx < 3; ++dx){
                int shift = (dy*10 + dx)*8;
                #pragma unroll
                for (int nf = 0; nf < 4; ++nf){
                    short8 B = *(const short8*)&actb[bro[nf] + shift];
                    #pragma unroll
                    for (int mf = 0; mf < 2; ++mf)
                        acc[mf][nf] = MFMA(A[dx][mf], B, acc[mf][nf]);
                }
            }
            __builtin_amdgcn_s_setprio(0);
        }
        if (cc < 15) stage_store();
    }

    if (DOWN){
        // fused 1x1 stride-2 downsample from x (NCHW f32), K=256 in 8 chunks.
        // dbuf reuses actb, granule-major: [cg][64 px][8], plane 808.
        for (int dc = 0; dc < 8; ++dc){
            #pragma unroll
            for (int it = 0; it < 16; ++it){
                int f = it*64 + lane;                // 1024 dword-pairs
                int cip = f >> 6, px2 = f & 63;
                int ipx = (px2>>3)*32 + (px2&7)*2;
                const float* src = &x[(((size_t)b*256 + dc*32 + 2*cip)*256) + ipx];
                *(u32*)&actb[(cip>>2)*808 + px2*8 + (cip&3)*2] = pack2(src[0], src[256]);
            }
            const u16* wdp = wpd + (size_t)(dc*512)*40 + abase;
            short8 A[2];
            #pragma unroll
            for (int mf = 0; mf < 2; ++mf)
                A[mf] = *(const short8*)&wdp[mf*640 + aoff];
            __builtin_amdgcn_s_setprio(1);
            #pragma unroll
            for (int nf = 0; nf < 4; ++nf){
                int rd = nf*16 + ln;
                short8 B = *(const short8*)&actb[kg*808 + rd*8];
                #pragma unroll
                for (int mf = 0; mf < 2; ++mf)
                    acc[mf][nf] = MFMA(A[mf], B, acc[mf][nf]);
            }
            __builtin_amdgcn_s_setprio(0);
        }
    }

    #pragma unroll
    for (int mf = 0; mf < 2; ++mf){
        int co0 = cot*32 + mf*16 + kg*4;
        float4 bv = *(const float4*)&bnb[co0];
        if (DOWN){
            float4 dv = *(const float4*)&dbb[co0];
            bv.x += dv.x; bv.y += dv.y; bv.z += dv.z; bv.w += dv.w;
        }
        #pragma unroll
        for (int nf = 0; nf < 4; ++nf){
            int px = nf*16 + ln;
            size_t o = (((size_t)b*64) + px)*512 + co0;
            f32x4 a = acc[mf][nf];
            float v0 = a[0] + bv.x, v1 = a[1] + bv.y;
            float v2 = a[2] + bv.z, v3 = a[3] + bv.w;
            if (RES){
                ushort4 rv = *(const ushort4*)&res[o];
                v0 += b2f(rv.x); v1 += b2f(rv.y); v2 += b2f(rv.z); v3 += b2f(rv.w);
            }
            ushort4 st;
            st.x = f2b(fmaxf(v0, 0.f)); st.y = f2b(fmaxf(v1, 0.f));
            st.z = f2b(fmaxf(v2, 0.f)); st.w = f2b(fmaxf(v3, 0.f));
            *(ushort4*)&out[o] = st;
        }
    }
}

// ---------------------------------------------------------------------------
// head: GAP(8x8) + linear 512->200 (unchanged).
// ---------------------------------------------------------------------------
__global__ __launch_bounds__(256)
void head_kernel(const u16* __restrict__ z, const float* __restrict__ hw,
                 float* __restrict__ pred)
{
    const int b = blockIdx.x, tid = threadIdx.x;
    __shared__ float feat[512];
    float s0 = 0.f, s1 = 0.f;
    for (int px = 0; px < 64; ++px){
        u32 u = *(const u32*)&z[(((size_t)b*64 + px)*512) + 2*tid];
        s0 += b2f((u16)(u & 0xFFFF));
        s1 += b2f((u16)(u >> 16));
    }
    feat[2*tid]   = s0 * (1.f/64.f);
    feat[2*tid+1] = s1 * (1.f/64.f);
    __syncthreads();
    if (tid < 200){
        float acc = 0.f;
        const float4* hp = (const float4*)&hw[(size_t)tid*512];
        #pragma unroll 8
        for (int i = 0; i < 128; ++i){
            float4 h = hp[i];
            float4 f = *(const float4*)&feat[i*4];
            acc += h.x*f.x + h.y*f.y + h.z*f.z + h.w*f.w;
        }
        pred[b*200 + tid] = acc;
    }
}

// ---------------------------------------------------------------------------
// gram: fused embed (emb LDS-resident) + Gram + sigmoid; setprio (r17).
// ---------------------------------------------------------------------------
__global__ __launch_bounds__(512, 2)
void gram_kernel(const float* __restrict__ x, const u16* __restrict__ wpe,
                 const float* __restrict__ eb, float* __restrict__ vol)
{
    const int b = blockIdx.x, tid = threadIdx.x;
    const int wid = tid >> 6, lane = tid & 63;
    const int ln = lane & 15, kg = lane >> 4;

    __shared__ u16 embl[256*136];        // 69,632 B
    __shared__ u16 xbl[256*40];          // 20,480 B
    __shared__ u16 ewl[128*40];          // 10,240 B

    f32x4 zero4 = {0.f,0.f,0.f,0.f};
    f32x4 ae[8][2];
    #pragma unroll
    for (int mf = 0; mf < 8; ++mf){ ae[mf][0] = zero4; ae[mf][1] = zero4; }

    for (int cc = 0; cc < 8; ++cc){
        __syncthreads();
        #pragma unroll
        for (int it = 0; it < 8; ++it){
            int f = it*512 + tid;
            int cip = f >> 8, px = f & 255;
            const float* src = &x[(((size_t)b*256 + cc*32 + 2*cip)*256) + px];
            *(u32*)&xbl[px*40 + 2*cip] = pack2(src[0], src[256]);
        }
        for (int j = tid; j < 640; j += 512)
            *(short8*)&ewl[j*8] = *(const short8*)&wpe[(cc*128)*40 + j*8];
        __syncthreads();
        short8 A[8];
        #pragma unroll
        for (int mf = 0; mf < 8; ++mf)
            A[mf] = *(const short8*)&ewl[(mf*16 + ln)*40 + kg*8];
        __builtin_amdgcn_s_setprio(1);
        #pragma unroll
        for (int nf = 0; nf < 2; ++nf){
            short8 B = *(const short8*)&xbl[(wid*32 + nf*16 + ln)*40 + kg*8];
            #pragma unroll
            for (int mf = 0; mf < 8; ++mf)
                ae[mf][nf] = MFMA(A[mf], B, ae[mf][nf]);
        }
        __builtin_amdgcn_s_setprio(0);
    }
    #pragma unroll
    for (int mf = 0; mf < 8; ++mf){
        int e0 = mf*16 + kg*4;
        float4 bv = *(const float4*)&eb[e0];
        #pragma unroll
        for (int nf = 0; nf < 2; ++nf){
            int px = wid*32 + nf*16 + ln;
            f32x4 a = ae[mf][nf];
            ushort4 st;
            st.x = f2b(a[0] + bv.x); st.y = f2b(a[1] + bv.y);
            st.z = f2b(a[2] + bv.z); st.w = f2b(a[3] + bv.w);
            *(ushort4*)&embl[px*136 + e0] = st;
        }
    }
    __syncthreads();

    const int wq = wid >> 2, wi = wid & 3;
    f32x4 g[8][4];
    #pragma unroll
    for (int mf = 0; mf < 8; ++mf)
        #pragma unroll
        for (int nf = 0; nf < 4; ++nf) g[mf][nf] = zero4;

    #pragma unroll
    for (int ks = 0; ks < 4; ++ks){
        short8 A[8];
        #pragma unroll
        for (int mf = 0; mf < 8; ++mf)
            A[mf] = *(const short8*)&embl[(wq*128 + mf*16 + ln)*136 + ks*32 + kg*8];
        __builtin_amdgcn_s_setprio(1);
        #pragma unroll
        for (int nf = 0; nf < 4; ++nf){
            short8 B = *(const short8*)&embl[(wi*64 + nf*16 + ln)*136 + ks*32 + kg*8];
            #pragma unroll
            for (int mf = 0; mf < 8; ++mf)
                g[mf][nf] = MFMA(A[mf], B, g[mf][nf]);
        }
        __builtin_amdgcn_s_setprio(0);
    }
    const float sc = 0.08838834764831845f;   // 1/sqrt(128)
    #pragma unroll
    for (int mf = 0; mf < 8; ++mf){
        #pragma unroll
        for (int nf = 0; nf < 4; ++nf){
            int i = wi*64 + nf*16 + ln;
            #pragma unroll
            for (int r = 0; r < 4; ++r){
                int q = wq*128 + mf*16 + kg*4 + r;
                vol[(((size_t)b*256 + q)*256) + i] = sigmoidf_(g[mf][nf][r] * sc);
            }
        }
    }
}

// ---------------------------------------------------------------------------
extern "C" void kernel_launch(void* const* d_in, const int* in_sizes, int n_in,
                              void* d_out, int out_size, void* d_ws, size_t ws_size,
                              hipStream_t stream)
{
    const float* x    = (const float*)d_in[0];
    const float* ew   = (const float*)d_in[1];
    const float* eb   = (const float*)d_in[2];
    const float* w1   = (const float*)d_in[3];
    const float* bn1s = (const float*)d_in[4];
    const float* bn1b = (const float*)d_in[5];
    const float* w2   = (const float*)d_in[6];
    const float* bn2s = (const float*)d_in[7];
    const float* bn2b = (const float*)d_in[8];
    const float* wd   = (const float*)d_in[9];
    const float* bnds = (const float*)d_in[10];
    const float* bndb = (const float*)d_in[11];
    const float* w3   = (const float*)d_in[12];
    const float* bn3s = (const float*)d_in[13];
    const float* bn3b = (const float*)d_in[14];
    const float* w4   = (const float*)d_in[15];
    const float* bn4s = (const float*)d_in[16];
    const float* bn4b = (const float*)d_in[17];
    const float* hw   = (const float*)d_in[18];

    float* pred = (float*)d_out;            // [256,200]
    float* vol  = pred + 51200;             // [256,256,256] f32

    u16* wp2 = (u16*)d_ws;
    u16* wp3 = wp2 + 2949120;
    u16* wp4 = wp3 + 2949120;
    u16* wp1 = wp4 + 2949120;
    u16* wpd = wp1 + 1474560;
    u16* wpe = wpd + 163840;

    u16* y1 = (u16*)vol;
    u16* y  = y1 + 8388608;
    u16* z1 = y  + 8388608;
    u16* z  = z1 + 8388608;

    prep_kernel<<<41120, 256, 0, stream>>>(w1, bn1s, w2, bn2s, w3, bn3s, w4, bn4s,
                                           wd, bnds, ew, wp1, wp2, wp3, wp4, wpd, wpe);
    conv1_kernel<<<dim3(128,2), 512, 0, stream>>>(x, wp1, bn1b, y1);
    conv_s1_kernel<1,0><<<4096, 64, 0, stream>>>(y1, wp2, bn2b, x, wpd, bndb,
                                                 nullptr, y);
    conv_s1_kernel<0,0><<<4096, 64, 0, stream>>>(y, wp3, bn3b, nullptr, nullptr,
                                                 nullptr, nullptr, z1);
    conv_s1_kernel<0,1><<<4096, 64, 0, stream>>>(z1, wp4, bn4b, nullptr, nullptr,
                                                 nullptr, y, z);
    head_kernel<<<256, 256, 0, stream>>>(z, hw, pred);
    gram_kernel<<<256, 512, 0, stream>>>(x, wpe, eb, vol);
}

// Round 19
// 368.095 us; speedup vs baseline: 1.0684x; 1.0684x over previous
//
#include <hip/hip_runtime.h>

// ---------------------------------------------------------------------------
// SelfConsistNet r19 = r17 (best: 347us) + conv_s1 FULL-CC A-HOIST:
//  - all 36 A-fragments of a cc loaded into named regs (A0/A1/A2, static
//    indices) BEFORE the dy compute loops; compiler schedules freely (r8's
//    failure was macro-forced order + buffer reuse, not hoisting per se).
//  - removes the ~200cyc A-latency bubble at each dy boundary: per-cc chain
//    max(load stream, 144 MFMA) instead of 3x(200+240).
//  - VGPR ~250 of 256 at launch_bounds(64,2). Spill = clean regression signal.
//  - r18's co-split reverted (B-LDS doubled, MFMA cluster halved: 140us).
// ---------------------------------------------------------------------------

using short8 = __attribute__((ext_vector_type(8))) short;   // 8 bf16 (4 VGPR)
using f32x4  = __attribute__((ext_vector_type(4))) float;   // MFMA acc
typedef unsigned short u16;
typedef unsigned int   u32;

#define MFMA(a,b,c) __builtin_amdgcn_mfma_f32_16x16x32_bf16((a),(b),(c),0,0,0)

__device__ __forceinline__ u16 f2b(float f){
    u32 u = __builtin_bit_cast(u32, f);
    u += 0x7FFFu + ((u >> 16) & 1u);        // RNE
    return (u16)(u >> 16);
}
__device__ __forceinline__ float b2f(u16 h){
    u32 u = ((u32)h) << 16;
    return __builtin_bit_cast(float, u);
}
__device__ __forceinline__ u32 pack2(float a, float b){
    return (u32)f2b(a) | ((u32)f2b(b) << 16);
}
__device__ __forceinline__ float sigmoidf_(float v){
    return 1.0f / (1.0f + __expf(-v));
}

// ---------------------------------------------------------------------------
// Weight prep (unchanged): bf16 [dydx][cc][co][40] fragment tiles, BN folded.
// ---------------------------------------------------------------------------
__global__ __launch_bounds__(256)
void prep_kernel(const float* __restrict__ w1, const float* __restrict__ s1,
                 const float* __restrict__ w2, const float* __restrict__ s2,
                 const float* __restrict__ w3, const float* __restrict__ s3,
                 const float* __restrict__ w4, const float* __restrict__ s4,
                 const float* __restrict__ wd, const float* __restrict__ sd,
                 const float* __restrict__ ew,
                 u16* __restrict__ wp1, u16* __restrict__ wp2,
                 u16* __restrict__ wp3, u16* __restrict__ wp4,
                 u16* __restrict__ wpd, u16* __restrict__ wpe)
{
    const int N2 = 9*16*512*40, N1 = 9*8*512*40, ND = 8*512*40, NE = 8*128*40;
    int t = blockIdx.x * 256 + threadIdx.x;
    if (t < N2) {
        int j = t % 40; int r = t / 40; int co = r & 511; int q = r >> 9;
        int cc = q & 15; int dydx = q >> 4;
        float v = (j < 32) ? w2[(co*512 + cc*32 + j)*9 + dydx] * s2[co] : 0.f;
        wp2[t] = f2b(v); return;
    }
    t -= N2;
    if (t < N2) {
        int j = t % 40; int r = t / 40; int co = r & 511; int q = r >> 9;
        int cc = q & 15; int dydx = q >> 4;
        float v = (j < 32) ? w3[(co*512 + cc*32 + j)*9 + dydx] * s3[co] : 0.f;
        wp3[t] = f2b(v); return;
    }
    t -= N2;
    if (t < N2) {
        int j = t % 40; int r = t / 40; int co = r & 511; int q = r >> 9;
        int cc = q & 15; int dydx = q >> 4;
        float v = (j < 32) ? w4[(co*512 + cc*32 + j)*9 + dydx] * s4[co] : 0.f;
        wp4[t] = f2b(v); return;
    }
    t -= N2;
    if (t < N1) {
        int j = t % 40; int r = t / 40; int co = r & 511; int q = r >> 9;
        int cc = q & 7; int dydx = q >> 3;
        float v = (j < 32) ? w1[(co*256 + cc*32 + j)*9 + dydx] * s1[co] : 0.f;
        wp1[t] = f2b(v); return;
    }
    t -= N1;
    if (t < ND) {
        int j = t % 40; int r = t / 40; int co = r & 511; int cc = r >> 9;
        float v = (j < 32) ? wd[co*256 + cc*32 + j] * sd[co] : 0.f;
        wpd[t] = f2b(v); return;
    }
    t -= ND;
    if (t < NE) {
        int j = t % 40; int r = t / 40; int e = r & 127; int cc = r >> 7;
        float v = (j < 32) ? ew[e*256 + cc*32 + j] : 0.f;
        wpe[t] = f2b(v);
    }
}

// ---------------------------------------------------------------------------
// K1: conv3x3 s2 (r17: grid (bpair,cot), setprio).
// ---------------------------------------------------------------------------
__global__ __launch_bounds__(512, 2)
void conv1_kernel(const float* __restrict__ x, const u16* __restrict__ wp,
                  const float* __restrict__ bnb, u16* __restrict__ out)
{
    const int b0  = blockIdx.x * 2;      // batch pair (XCD = bid%8 = bp%8)
    const int cot = blockIdx.y;          // 0..1
    const int tid = threadIdx.x;
    const int wid = tid >> 6, lane = tid & 63;
    const int ln = lane & 15, kg = lane >> 4;
    const int wco = wid >> 1;            // 0..3
    const int bb  = wid & 1;             // 0..1

    __shared__ u16 actb[2][2*289*40];    // 92,480 B

    {
        short8 zz = {0,0,0,0,0,0,0,0};
        short8* ab = (short8*)&actb[0][0];
        for (int j = tid; j < 2*2*289*40/8; j += 512) ab[j] = zz;
    }
    __syncthreads();

    auto stage_act = [&](int cc, int p){
        #pragma unroll
        for (int it = 0; it < 16; ++it){
            int f = it*512 + tid;                    // 8192 dwords
            int bb2 = f >> 12; int rem = f & 4095;
            int cip = rem >> 8; int px = rem & 255;
            const float* src = &x[(((size_t)(b0+bb2)*256 + cc*32 + 2*cip)*256) + px];
            float v0 = src[0], v1 = src[256];
            int r = ((px >> 4) + 1)*17 + (px & 15) + 1;
            *(u32*)&actb[p][(bb2*289 + r)*40 + 2*cip] = pack2(v0, v1);
        }
    };

    stage_act(0, 0);
    __syncthreads();

    f32x4 zero4 = {0.f,0.f,0.f,0.f};
    f32x4 acc[4][4];
    #pragma unroll
    for (int mf = 0; mf < 4; ++mf)
        #pragma unroll
        for (int nf = 0; nf < 4; ++nf) acc[mf][nf] = zero4;

    int bbase[4];
    #pragma unroll
    for (int nf = 0; nf < 4; ++nf){
        int px = nf*16 + ln;
        bbase[nf] = (bb*289 + 34*(px>>3) + 2*(px&7))*40 + kg*8;
    }

    for (int cc = 0; cc < 8; ++cc){
        if (cc < 7) stage_act(cc+1, (cc+1) & 1);
        const u16* abp = actb[cc & 1];
        #pragma unroll
        for (int d = 0; d < 9; ++d){
            const u16* wdp = wp + ((size_t)(d*8 + cc)*512 + cot*256)*40;
            int dy = d/3, dx = d - dy*3;
            int shift = (dy*17 + dx)*40;
            short8 A[4];
            #pragma unroll
            for (int mf = 0; mf < 4; ++mf)
                A[mf] = *(const short8*)&wdp[(wco*64 + mf*16 + ln)*40 + kg*8];
            __builtin_amdgcn_s_setprio(1);
            #pragma unroll
            for (int nf = 0; nf < 4; ++nf){
                short8 B = *(const short8*)&abp[bbase[nf] + shift];
                #pragma unroll
                for (int mf = 0; mf < 4; ++mf)
                    acc[mf][nf] = MFMA(A[mf], B, acc[mf][nf]);
            }
            __builtin_amdgcn_s_setprio(0);
        }
        __syncthreads();
    }

    #pragma unroll
    for (int mf = 0; mf < 4; ++mf){
        int co0 = cot*256 + wco*64 + mf*16 + kg*4;
        float4 bv = *(const float4*)&bnb[co0];
        #pragma unroll
        for (int nf = 0; nf < 4; ++nf){
            int px = nf*16 + ln;
            size_t o = (((size_t)(b0+bb)*64) + px)*512 + co0;
            f32x4 a = acc[mf][nf];
            ushort4 st;
            st.x = f2b(fmaxf(a[0] + bv.x, 0.f));
            st.y = f2b(fmaxf(a[1] + bv.y, 0.f));
            st.z = f2b(fmaxf(a[2] + bv.z, 0.f));
            st.w = f2b(fmaxf(a[3] + bv.w, 0.f));
            *(ushort4*)&out[o] = st;
        }
    }
}

// ---------------------------------------------------------------------------
// K2/K3/K4 (r19): r17 structure + full-cc A-hoist (36 frags in named regs).
// Granule-major LDS [cg][101][8] (plane 808, dbuf); remapped 1D grid 2048;
// single-wave blocks 64co x 64px; setprio on the 144-MFMA cc cluster.
// ---------------------------------------------------------------------------
template<int DOWN, int RES>
__global__ __launch_bounds__(64, 2)
void conv_s1_kernel(const u16* __restrict__ in, const u16* __restrict__ wp,
                    const float* __restrict__ bnb,
                    const float* __restrict__ x, const u16* __restrict__ wpd,
                    const float* __restrict__ dbb,
                    const u16* __restrict__ res, u16* __restrict__ out)
{
    const int bid = blockIdx.x;          // 0..2047
    const int cot = (bid >> 3) & 7;      // 0..7 (64 co)
    const int b   = (bid & 7) | ((bid >> 6) << 3);   // 0..255; XCD = b%8
    const int lane = threadIdx.x;        // 0..63, single wave
    const int ln = lane & 15, kg = lane >> 4;

    __shared__ u16 actb[2][3232];        // [cg][101][8] x2, 12,928 B

    {
        short8 zz = {0,0,0,0,0,0,0,0};
        short8* ab = (short8*)&actb[0][0];
        #pragma unroll
        for (int it = 0; it < 13; ++it){
            int j = it*64 + lane;
            if (j < 808) ab[j] = zz;
        }
    }

    // staging: 256 short8 per cc-chunk, 4 per lane; dest [cg][row][8]
    int s_ld[4]; size_t s_go[4];
    #pragma unroll
    for (int it = 0; it < 4; ++it){
        int j = it*64 + lane;
        int px = j >> 2, cg = j & 3;
        int row = ((px>>3)+1)*10 + (px&7) + 1;       // interior 11..88
        s_ld[it] = cg*808 + row*8;
        s_go[it] = (((size_t)b*64 + px)*512) + cg*8;
    }

    short8 sreg[4];
    auto stage_load = [&](int cc){
        #pragma unroll
        for (int it = 0; it < 4; ++it)
            sreg[it] = *(const short8*)&in[s_go[it] + cc*32];
    };
    auto stage_store = [&](int p){
        #pragma unroll
        for (int it = 0; it < 4; ++it)
            *(short8*)&actb[p][s_ld[it]] = sreg[it];
    };

    stage_load(0); stage_store(0);

    f32x4 zero4 = {0.f,0.f,0.f,0.f};
    f32x4 acc[4][4];
    #pragma unroll
    for (int mf = 0; mf < 4; ++mf)
        #pragma unroll
        for (int nf = 0; nf < 4; ++nf) acc[mf][nf] = zero4;

    int bro[4];
    #pragma unroll
    for (int nf = 0; nf < 4; ++nf){
        int px = nf*16 + ln;
        bro[nf] = kg*808 + ((px>>3)*10 + (px&7))*8;
    }
    const int aoff = ln*40 + kg*8;
    const int abase = cot*64*40;

    auto loadA12 = [&](short8 (&A)[3][4], int cc, int dy){
        #pragma unroll
        for (int dx = 0; dx < 3; ++dx){
            const u16* wdp = wp + (size_t)((dy*3+dx)*16 + cc)*512*40 + abase;
            #pragma unroll
            for (int mf = 0; mf < 4; ++mf)
                A[dx][mf] = *(const short8*)&wdp[mf*640 + aoff];
        }
    };

    for (int cc = 0; cc < 16; ++cc){
        if (cc < 15) stage_load(cc+1);
        const u16* abp = actb[cc & 1];
        // full-cc A-hoist: all 36 fragments before any MFMA of this cc
        short8 A0[3][4], A1[3][4], A2[3][4];
        loadA12(A0, cc, 0);
        loadA12(A1, cc, 1);
        loadA12(A2, cc, 2);
        __builtin_amdgcn_s_setprio(1);
        #pragma unroll
        for (int dx = 0; dx < 3; ++dx){
            int shift = dx*8;
            #pragma unroll
            for (int nf = 0; nf < 4; ++nf){
                short8 B = *(const short8*)&abp[bro[nf] + shift];
                #pragma unroll
                for (int mf = 0; mf < 4; ++mf)
                    acc[mf][nf] = MFMA(A0[dx][mf], B, acc[mf][nf]);
            }
        }
        #pragma unroll
        for (int dx = 0; dx < 3; ++dx){
            int shift = (10 + dx)*8;
            #pragma unroll
            for (int nf = 0; nf < 4; ++nf){
                short8 B = *(const short8*)&abp[bro[nf] + shift];
                #pragma unroll
                for (int mf = 0; mf < 4; ++mf)
                    acc[mf][nf] = MFMA(A1[dx][mf], B, acc[mf][nf]);
            }
        }
        #pragma unroll
        for (int dx = 0; dx < 3; ++dx){
            int shift = (20 + dx)*8;
            #pragma unroll
            for (int nf = 0; nf < 4; ++nf){
                short8 B = *(const short8*)&abp[bro[nf] + shift];
                #pragma unroll
                for (int mf = 0; mf < 4; ++mf)
                    acc[mf][nf] = MFMA(A2[dx][mf], B, acc[mf][nf]);
            }
        }
        __builtin_amdgcn_s_setprio(0);
        if (cc < 15) stage_store((cc+1) & 1);
    }

    if (DOWN){
        // fused 1x1 stride-2 downsample from x (NCHW f32), K=256 in 8 chunks.
        for (int dc = 0; dc < 8; ++dc){
            #pragma unroll
            for (int it = 0; it < 16; ++it){
                int f = it*64 + lane;                // 1024 dword-pairs
                int cip = f >> 6, px2 = f & 63;
                int ipx = (px2>>3)*32 + (px2&7)*2;
                const float* src = &x[(((size_t)b*256 + dc*32 + 2*cip)*256) + ipx];
                *(u32*)&actb[0][(cip>>2)*808 + px2*8 + (cip&3)*2] = pack2(src[0], src[256]);
            }
            const u16* wdp = wpd + (size_t)(dc*512)*40 + abase;
            short8 A[4];
            #pragma unroll
            for (int mf = 0; mf < 4; ++mf)
                A[mf] = *(const short8*)&wdp[mf*640 + aoff];
            __builtin_amdgcn_s_setprio(1);
            #pragma unroll
            for (int nf = 0; nf < 4; ++nf){
                int rd = nf*16 + ln;
                short8 B = *(const short8*)&actb[0][kg*808 + rd*8];
                #pragma unroll
                for (int mf = 0; mf < 4; ++mf)
                    acc[mf][nf] = MFMA(A[mf], B, acc[mf][nf]);
            }
            __builtin_amdgcn_s_setprio(0);
        }
    }

    #pragma unroll
    for (int mf = 0; mf < 4; ++mf){
        int co0 = cot*64 + mf*16 + kg*4;
        float4 bv = *(const float4*)&bnb[co0];
        if (DOWN){
            float4 dv = *(const float4*)&dbb[co0];
            bv.x += dv.x; bv.y += dv.y; bv.z += dv.z; bv.w += dv.w;
        }
        #pragma unroll
        for (int nf = 0; nf < 4; ++nf){
            int px = nf*16 + ln;
            size_t o = (((size_t)b*64) + px)*512 + co0;
            f32x4 a = acc[mf][nf];
            float v0 = a[0] + bv.x, v1 = a[1] + bv.y;
            float v2 = a[2] + bv.z, v3 = a[3] + bv.w;
            if (RES){
                ushort4 rv = *(const ushort4*)&res[o];
                v0 += b2f(rv.x); v1 += b2f(rv.y); v2 += b2f(rv.z); v3 += b2f(rv.w);
            }
            ushort4 st;
            st.x = f2b(fmaxf(v0, 0.f)); st.y = f2b(fmaxf(v1, 0.f));
            st.z = f2b(fmaxf(v2, 0.f)); st.w = f2b(fmaxf(v3, 0.f));
            *(ushort4*)&out[o] = st;
        }
    }
}

// ---------------------------------------------------------------------------
// head: GAP(8x8) + linear 512->200 (unchanged).
// ---------------------------------------------------------------------------
__global__ __launch_bounds__(256)
void head_kernel(const u16* __restrict__ z, const float* __restrict__ hw,
                 float* __restrict__ pred)
{
    const int b = blockIdx.x, tid = threadIdx.x;
    __shared__ float feat[512];
    float s0 = 0.f, s1 = 0.f;
    for (int px = 0; px < 64; ++px){
        u32 u = *(const u32*)&z[(((size_t)b*64 + px)*512) + 2*tid];
        s0 += b2f((u16)(u & 0xFFFF));
        s1 += b2f((u16)(u >> 16));
    }
    feat[2*tid]   = s0 * (1.f/64.f);
    feat[2*tid+1] = s1 * (1.f/64.f);
    __syncthreads();
    if (tid < 200){
        float acc = 0.f;
        const float4* hp = (const float4*)&hw[(size_t)tid*512];
        #pragma unroll 8
        for (int i = 0; i < 128; ++i){
            float4 h = hp[i];
            float4 f = *(const float4*)&feat[i*4];
            acc += h.x*f.x + h.y*f.y + h.z*f.z + h.w*f.w;
        }
        pred[b*200 + tid] = acc;
    }
}

// ---------------------------------------------------------------------------
// gram: fused embed (emb LDS-resident) + Gram + sigmoid; setprio (r17).
// ---------------------------------------------------------------------------
__global__ __launch_bounds__(512, 2)
void gram_kernel(const float* __restrict__ x, const u16* __restrict__ wpe,
                 const float* __restrict__ eb, float* __restrict__ vol)
{
    const int b = blockIdx.x, tid = threadIdx.x;
    const int wid = tid >> 6, lane = tid & 63;
    const int ln = lane & 15, kg = lane >> 4;

    __shared__ u16 embl[256*136];        // 69,632 B
    __shared__ u16 xbl[256*40];          // 20,480 B
    __shared__ u16 ewl[128*40];          // 10,240 B

    f32x4 zero4 = {0.f,0.f,0.f,0.f};
    f32x4 ae[8][2];
    #pragma unroll
    for (int mf = 0; mf < 8; ++mf){ ae[mf][0] = zero4; ae[mf][1] = zero4; }

    for (int cc = 0; cc < 8; ++cc){
        __syncthreads();
        #pragma unroll
        for (int it = 0; it < 8; ++it){
            int f = it*512 + tid;
            int cip = f >> 8, px = f & 255;
            const float* src = &x[(((size_t)b*256 + cc*32 + 2*cip)*256) + px];
            *(u32*)&xbl[px*40 + 2*cip] = pack2(src[0], src[256]);
        }
        for (int j = tid; j < 640; j += 512)
            *(short8*)&ewl[j*8] = *(const short8*)&wpe[(cc*128)*40 + j*8];
        __syncthreads();
        short8 A[8];
        #pragma unroll
        for (int mf = 0; mf < 8; ++mf)
            A[mf] = *(const short8*)&ewl[(mf*16 + ln)*40 + kg*8];
        __builtin_amdgcn_s_setprio(1);
        #pragma unroll
        for (int nf = 0; nf < 2; ++nf){
            short8 B = *(const short8*)&xbl[(wid*32 + nf*16 + ln)*40 + kg*8];
            #pragma unroll
            for (int mf = 0; mf < 8; ++mf)
                ae[mf][nf] = MFMA(A[mf], B, ae[mf][nf]);
        }
        __builtin_amdgcn_s_setprio(0);
    }
    #pragma unroll
    for (int mf = 0; mf < 8; ++mf){
        int e0 = mf*16 + kg*4;
        float4 bv = *(const float4*)&eb[e0];
        #pragma unroll
        for (int nf = 0; nf < 2; ++nf){
            int px = wid*32 + nf*16 + ln;
            f32x4 a = ae[mf][nf];
            ushort4 st;
            st.x = f2b(a[0] + bv.x); st.y = f2b(a[1] + bv.y);
            st.z = f2b(a[2] + bv.z); st.w = f2b(a[3] + bv.w);
            *(ushort4*)&embl[px*136 + e0] = st;
        }
    }
    __syncthreads();

    const int wq = wid >> 2, wi = wid & 3;
    f32x4 g[8][4];
    #pragma unroll
    for (int mf = 0; mf < 8; ++mf)
        #pragma unroll
        for (int nf = 0; nf < 4; ++nf) g[mf][nf] = zero4;

    #pragma unroll
    for (int ks = 0; ks < 4; ++ks){
        short8 A[8];
        #pragma unroll
        for (int mf = 0; mf < 8; ++mf)
            A[mf] = *(const short8*)&embl[(wq*128 + mf*16 + ln)*136 + ks*32 + kg*8];
        __builtin_amdgcn_s_setprio(1);
        #pragma unroll
        for (int nf = 0; nf < 4; ++nf){
            short8 B = *(const short8*)&embl[(wi*64 + nf*16 + ln)*136 + ks*32 + kg*8];
            #pragma unroll
            for (int mf = 0; mf < 8; ++mf)
                g[mf][nf] = MFMA(A[mf], B, g[mf][nf]);
        }
        __builtin_amdgcn_s_setprio(0);
    }
    const float sc = 0.08838834764831845f;   // 1/sqrt(128)
    #pragma unroll
    for (int mf = 0; mf < 8; ++mf){
        #pragma unroll
        for (int nf = 0; nf < 4; ++nf){
            int i = wi*64 + nf*16 + ln;
            #pragma unroll
            for (int r = 0; r < 4; ++r){
                int q = wq*128 + mf*16 + kg*4 + r;
                vol[(((size_t)b*256 + q)*256) + i] = sigmoidf_(g[mf][nf][r] * sc);
            }
        }
    }
}

// ---------------------------------------------------------------------------
extern "C" void kernel_launch(void* const* d_in, const int* in_sizes, int n_in,
                              void* d_out, int out_size, void* d_ws, size_t ws_size,
                              hipStream_t stream)
{
    const float* x    = (const float*)d_in[0];
    const float* ew   = (const float*)d_in[1];
    const float* eb   = (const float*)d_in[2];
    const float* w1   = (const float*)d_in[3];
    const float* bn1s = (const float*)d_in[4];
    const float* bn1b = (const float*)d_in[5];
    const float* w2   = (const float*)d_in[6];
    const float* bn2s = (const float*)d_in[7];
    const float* bn2b = (const float*)d_in[8];
    const float* wd   = (const float*)d_in[9];
    const float* bnds = (const float*)d_in[10];
    const float* bndb = (const float*)d_in[11];
    const float* w3   = (const float*)d_in[12];
    const float* bn3s = (const float*)d_in[13];
    const float* bn3b = (const float*)d_in[14];
    const float* w4   = (const float*)d_in[15];
    const float* bn4s = (const float*)d_in[16];
    const float* bn4b = (const float*)d_in[17];
    const float* hw   = (const float*)d_in[18];

    float* pred = (float*)d_out;            // [256,200]
    float* vol  = pred + 51200;             // [256,256,256] f32

    u16* wp2 = (u16*)d_ws;
    u16* wp3 = wp2 + 2949120;
    u16* wp4 = wp3 + 2949120;
    u16* wp1 = wp4 + 2949120;
    u16* wpd = wp1 + 1474560;
    u16* wpe = wpd + 163840;

    u16* y1 = (u16*)vol;
    u16* y  = y1 + 8388608;
    u16* z1 = y  + 8388608;
    u16* z  = z1 + 8388608;

    prep_kernel<<<41120, 256, 0, stream>>>(w1, bn1s, w2, bn2s, w3, bn3s, w4, bn4s,
                                           wd, bnds, ew, wp1, wp2, wp3, wp4, wpd, wpe);
    conv1_kernel<<<dim3(128,2), 512, 0, stream>>>(x, wp1, bn1b, y1);
    conv_s1_kernel<1,0><<<2048, 64, 0, stream>>>(y1, wp2, bn2b, x, wpd, bndb,
                                                 nullptr, y);
    conv_s1_kernel<0,0><<<2048, 64, 0, stream>>>(y, wp3, bn3b, nullptr, nullptr,
                                                 nullptr, nullptr, z1);
    conv_s1_kernel<0,1><<<2048, 64, 0, stream>>>(z1, wp4, bn4b, nullptr, nullptr,
                                                 nullptr, y, z);
    head_kernel<<<256, 256, 0, stream>>>(z, hw, pred);
    gram_kernel<<<256, 512, 0, stream>>>(x, wpe, eb, vol);
}

// Round 20
// 346.241 us; speedup vs baseline: 1.1359x; 1.0631x over previous
//
#include <hip/hip_runtime.h>

// ---------------------------------------------------------------------------
// SelfConsistNet r20 = r17 restored (best: 347us, placeholder dead-code
// removed) + conv_s1 setprio level 1 -> 2 (one variable; priority 0..3,
// higher level can only strengthen the proven arbitration win).
// r19's full-cc A-hoist reverted (compiler caps 128 VGPR, serializes: 368us).
// Final structure: single-wave 64co x 64px conv blocks, remapped grid
// (XCD=b%8 AND co-resident blocks share cot), granule-major LDS
// [cg][101][8] plane 808, per-dy compiler-scheduled A-preload, setprio.
// ---------------------------------------------------------------------------

using short8 = __attribute__((ext_vector_type(8))) short;   // 8 bf16 (4 VGPR)
using f32x4  = __attribute__((ext_vector_type(4))) float;   // MFMA acc
typedef unsigned short u16;
typedef unsigned int   u32;

#define MFMA(a,b,c) __builtin_amdgcn_mfma_f32_16x16x32_bf16((a),(b),(c),0,0,0)

__device__ __forceinline__ u16 f2b(float f){
    u32 u = __builtin_bit_cast(u32, f);
    u += 0x7FFFu + ((u >> 16) & 1u);        // RNE
    return (u16)(u >> 16);
}
__device__ __forceinline__ float b2f(u16 h){
    u32 u = ((u32)h) << 16;
    return __builtin_bit_cast(float, u);
}
__device__ __forceinline__ u32 pack2(float a, float b){
    return (u32)f2b(a) | ((u32)f2b(b) << 16);
}
__device__ __forceinline__ float sigmoidf_(float v){
    return 1.0f / (1.0f + __expf(-v));
}

// ---------------------------------------------------------------------------
// Weight prep: bf16 [dydx][cc][co][40] fragment tiles, BN scale folded.
// ---------------------------------------------------------------------------
__global__ __launch_bounds__(256)
void prep_kernel(const float* __restrict__ w1, const float* __restrict__ s1,
                 const float* __restrict__ w2, const float* __restrict__ s2,
                 const float* __restrict__ w3, const float* __restrict__ s3,
                 const float* __restrict__ w4, const float* __restrict__ s4,
                 const float* __restrict__ wd, const float* __restrict__ sd,
                 const float* __restrict__ ew,
                 u16* __restrict__ wp1, u16* __restrict__ wp2,
                 u16* __restrict__ wp3, u16* __restrict__ wp4,
                 u16* __restrict__ wpd, u16* __restrict__ wpe)
{
    const int N2 = 9*16*512*40, N1 = 9*8*512*40, ND = 8*512*40, NE = 8*128*40;
    int t = blockIdx.x * 256 + threadIdx.x;
    if (t < N2) {
        int j = t % 40; int r = t / 40; int co = r & 511; int q = r >> 9;
        int cc = q & 15; int dydx = q >> 4;
        float v = (j < 32) ? w2[(co*512 + cc*32 + j)*9 + dydx] * s2[co] : 0.f;
        wp2[t] = f2b(v); return;
    }
    t -= N2;
    if (t < N2) {
        int j = t % 40; int r = t / 40; int co = r & 511; int q = r >> 9;
        int cc = q & 15; int dydx = q >> 4;
        float v = (j < 32) ? w3[(co*512 + cc*32 + j)*9 + dydx] * s3[co] : 0.f;
        wp3[t] = f2b(v); return;
    }
    t -= N2;
    if (t < N2) {
        int j = t % 40; int r = t / 40; int co = r & 511; int q = r >> 9;
        int cc = q & 15; int dydx = q >> 4;
        float v = (j < 32) ? w4[(co*512 + cc*32 + j)*9 + dydx] * s4[co] : 0.f;
        wp4[t] = f2b(v); return;
    }
    t -= N2;
    if (t < N1) {
        int j = t % 40; int r = t / 40; int co = r & 511; int q = r >> 9;
        int cc = q & 7; int dydx = q >> 3;
        float v = (j < 32) ? w1[(co*256 + cc*32 + j)*9 + dydx] * s1[co] : 0.f;
        wp1[t] = f2b(v); return;
    }
    t -= N1;
    if (t < ND) {
        int j = t % 40; int r = t / 40; int co = r & 511; int cc = r >> 9;
        float v = (j < 32) ? wd[co*256 + cc*32 + j] * sd[co] : 0.f;
        wpd[t] = f2b(v); return;
    }
    t -= ND;
    if (t < NE) {
        int j = t % 40; int r = t / 40; int e = r & 127; int cc = r >> 7;
        float v = (j < 32) ? ew[e*256 + cc*32 + j] : 0.f;
        wpe[t] = f2b(v);
    }
}

// ---------------------------------------------------------------------------
// K1: conv3x3 s2; grid (bpair=128, cot=2) same-XCD x sharing; setprio(1).
// ---------------------------------------------------------------------------
__global__ __launch_bounds__(512, 2)
void conv1_kernel(const float* __restrict__ x, const u16* __restrict__ wp,
                  const float* __restrict__ bnb, u16* __restrict__ out)
{
    const int b0  = blockIdx.x * 2;      // batch pair (XCD = bid%8 = bp%8)
    const int cot = blockIdx.y;          // 0..1
    const int tid = threadIdx.x;
    const int wid = tid >> 6, lane = tid & 63;
    const int ln = lane & 15, kg = lane >> 4;
    const int wco = wid >> 1;            // 0..3
    const int bb  = wid & 1;             // 0..1

    __shared__ u16 actb[2][2*289*40];    // 92,480 B

    {
        short8 zz = {0,0,0,0,0,0,0,0};
        short8* ab = (short8*)&actb[0][0];
        for (int j = tid; j < 2*2*289*40/8; j += 512) ab[j] = zz;
    }
    __syncthreads();

    auto stage_act = [&](int cc, int p){
        #pragma unroll
        for (int it = 0; it < 16; ++it){
            int f = it*512 + tid;                    // 8192 dwords
            int bb2 = f >> 12; int rem = f & 4095;
            int cip = rem >> 8; int px = rem & 255;
            const float* src = &x[(((size_t)(b0+bb2)*256 + cc*32 + 2*cip)*256) + px];
            float v0 = src[0], v1 = src[256];
            int r = ((px >> 4) + 1)*17 + (px & 15) + 1;
            *(u32*)&actb[p][(bb2*289 + r)*40 + 2*cip] = pack2(v0, v1);
        }
    };

    stage_act(0, 0);
    __syncthreads();

    f32x4 zero4 = {0.f,0.f,0.f,0.f};
    f32x4 acc[4][4];
    #pragma unroll
    for (int mf = 0; mf < 4; ++mf)
        #pragma unroll
        for (int nf = 0; nf < 4; ++nf) acc[mf][nf] = zero4;

    int bbase[4];
    #pragma unroll
    for (int nf = 0; nf < 4; ++nf){
        int px = nf*16 + ln;
        bbase[nf] = (bb*289 + 34*(px>>3) + 2*(px&7))*40 + kg*8;
    }

    for (int cc = 0; cc < 8; ++cc){
        if (cc < 7) stage_act(cc+1, (cc+1) & 1);
        const u16* abp = actb[cc & 1];
        #pragma unroll
        for (int d = 0; d < 9; ++d){
            const u16* wdp = wp + ((size_t)(d*8 + cc)*512 + cot*256)*40;
            int dy = d/3, dx = d - dy*3;
            int shift = (dy*17 + dx)*40;
            short8 A[4];
            #pragma unroll
            for (int mf = 0; mf < 4; ++mf)
                A[mf] = *(const short8*)&wdp[(wco*64 + mf*16 + ln)*40 + kg*8];
            __builtin_amdgcn_s_setprio(1);
            #pragma unroll
            for (int nf = 0; nf < 4; ++nf){
                short8 B = *(const short8*)&abp[bbase[nf] + shift];
                #pragma unroll
                for (int mf = 0; mf < 4; ++mf)
                    acc[mf][nf] = MFMA(A[mf], B, acc[mf][nf]);
            }
            __builtin_amdgcn_s_setprio(0);
        }
        __syncthreads();
    }

    #pragma unroll
    for (int mf = 0; mf < 4; ++mf){
        int co0 = cot*256 + wco*64 + mf*16 + kg*4;
        float4 bv = *(const float4*)&bnb[co0];
        #pragma unroll
        for (int nf = 0; nf < 4; ++nf){
            int px = nf*16 + ln;
            size_t o = (((size_t)(b0+bb)*64) + px)*512 + co0;
            f32x4 a = acc[mf][nf];
            ushort4 st;
            st.x = f2b(fmaxf(a[0] + bv.x, 0.f));
            st.y = f2b(fmaxf(a[1] + bv.y, 0.f));
            st.z = f2b(fmaxf(a[2] + bv.z, 0.f));
            st.w = f2b(fmaxf(a[3] + bv.w, 0.f));
            *(ushort4*)&out[o] = st;
        }
    }
}

// ---------------------------------------------------------------------------
// K2/K3/K4: r17 structure; setprio level 2 on MFMA clusters.
// Granule-major LDS [cg][101][8] (plane 808, dbuf); remapped 1D grid 2048:
//   cot = (bid>>3)&7;  b = (bid&7) | ((bid>>6)<<3); XCD = b%8.
// ---------------------------------------------------------------------------
template<int DOWN, int RES>
__global__ __launch_bounds__(64, 2)
void conv_s1_kernel(const u16* __restrict__ in, const u16* __restrict__ wp,
                    const float* __restrict__ bnb,
                    const float* __restrict__ x, const u16* __restrict__ wpd,
                    const float* __restrict__ dbb,
                    const u16* __restrict__ res, u16* __restrict__ out)
{
    const int bid = blockIdx.x;          // 0..2047
    const int cot = (bid >> 3) & 7;      // 0..7 (64 co)
    const int b   = (bid & 7) | ((bid >> 6) << 3);   // 0..255; XCD = b%8
    const int lane = threadIdx.x;        // 0..63, single wave
    const int ln = lane & 15, kg = lane >> 4;

    __shared__ u16 actb[2][3232];        // [cg][101][8] x2, 12,928 B

    {
        short8 zz = {0,0,0,0,0,0,0,0};
        short8* ab = (short8*)&actb[0][0];
        #pragma unroll
        for (int it = 0; it < 13; ++it){
            int j = it*64 + lane;
            if (j < 808) ab[j] = zz;
        }
    }

    // staging: 256 short8 per cc-chunk, 4 per lane; dest [cg][row][8]
    int s_ld[4]; size_t s_go[4];
    #pragma unroll
    for (int it = 0; it < 4; ++it){
        int j = it*64 + lane;
        int px = j >> 2, cg = j & 3;
        int row = ((px>>3)+1)*10 + (px&7) + 1;       // interior 11..88
        s_ld[it] = cg*808 + row*8;
        s_go[it] = (((size_t)b*64 + px)*512) + cg*8;
    }

    short8 sreg[4];
    auto stage_load = [&](int cc){
        #pragma unroll
        for (int it = 0; it < 4; ++it)
            sreg[it] = *(const short8*)&in[s_go[it] + cc*32];
    };
    auto stage_store = [&](int p){
        #pragma unroll
        for (int it = 0; it < 4; ++it)
            *(short8*)&actb[p][s_ld[it]] = sreg[it];
    };

    stage_load(0); stage_store(0);

    f32x4 zero4 = {0.f,0.f,0.f,0.f};
    f32x4 acc[4][4];
    #pragma unroll
    for (int mf = 0; mf < 4; ++mf)
        #pragma unroll
        for (int nf = 0; nf < 4; ++nf) acc[mf][nf] = zero4;

    int bro[4];
    #pragma unroll
    for (int nf = 0; nf < 4; ++nf){
        int px = nf*16 + ln;
        bro[nf] = kg*808 + ((px>>3)*10 + (px&7))*8;
    }
    const int aoff = ln*40 + kg*8;
    const int abase = cot*64*40;

    for (int cc = 0; cc < 16; ++cc){
        if (cc < 15) stage_load(cc+1);
        const u16* abp = actb[cc & 1];
        #pragma unroll
        for (int dy = 0; dy < 3; ++dy){
            // preload all 12 A-fragments for this dy (3 dx x 4 mf)
            short8 A[3][4];
            #pragma unroll
            for (int dx = 0; dx < 3; ++dx){
                const u16* wdp = wp + (size_t)((dy*3+dx)*16 + cc)*512*40 + abase;
                #pragma unroll
                for (int mf = 0; mf < 4; ++mf)
                    A[dx][mf] = *(const short8*)&wdp[mf*640 + aoff];
            }
            __builtin_amdgcn_s_setprio(2);
            #pragma unroll
            for (int dx = 0; dx < 3; ++dx){
                int shift = (dy*10 + dx)*8;
                #pragma unroll
                for (int nf = 0; nf < 4; ++nf){
                    short8 B = *(const short8*)&abp[bro[nf] + shift];
                    #pragma unroll
                    for (int mf = 0; mf < 4; ++mf)
                        acc[mf][nf] = MFMA(A[dx][mf], B, acc[mf][nf]);
                }
            }
            __builtin_amdgcn_s_setprio(0);
        }
        if (cc < 15) stage_store((cc+1) & 1);
    }

    if (DOWN){
        // fused 1x1 stride-2 downsample from x (NCHW f32), K=256 in 8 chunks.
        for (int dc = 0; dc < 8; ++dc){
            #pragma unroll
            for (int it = 0; it < 16; ++it){
                int f = it*64 + lane;                // 1024 dword-pairs
                int cip = f >> 6, px2 = f & 63;
                int ipx = (px2>>3)*32 + (px2&7)*2;
                const float* src = &x[(((size_t)b*256 + dc*32 + 2*cip)*256) + ipx];
                *(u32*)&actb[0][(cip>>2)*808 + px2*8 + (cip&3)*2] = pack2(src[0], src[256]);
            }
            const u16* wdp = wpd + (size_t)(dc*512)*40 + abase;
            short8 A[4];
            #pragma unroll
            for (int mf = 0; mf < 4; ++mf)
                A[mf] = *(const short8*)&wdp[mf*640 + aoff];
            __builtin_amdgcn_s_setprio(2);
            #pragma unroll
            for (int nf = 0; nf < 4; ++nf){
                int rd = nf*16 + ln;
                short8 B = *(const short8*)&actb[0][kg*808 + rd*8];
                #pragma unroll
                for (int mf = 0; mf < 4; ++mf)
                    acc[mf][nf] = MFMA(A[mf], B, acc[mf][nf]);
            }
            __builtin_amdgcn_s_setprio(0);
        }
    }

    #pragma unroll
    for (int mf = 0; mf < 4; ++mf){
        int co0 = cot*64 + mf*16 + kg*4;
        float4 bv = *(const float4*)&bnb[co0];
        if (DOWN){
            float4 dv = *(const float4*)&dbb[co0];
            bv.x += dv.x; bv.y += dv.y; bv.z += dv.z; bv.w += dv.w;
        }
        #pragma unroll
        for (int nf = 0; nf < 4; ++nf){
            int px = nf*16 + ln;
            size_t o = (((size_t)b*64) + px)*512 + co0;
            f32x4 a = acc[mf][nf];
            float v0 = a[0] + bv.x, v1 = a[1] + bv.y;
            float v2 = a[2] + bv.z, v3 = a[3] + bv.w;
            if (RES){
                ushort4 rv = *(const ushort4*)&res[o];
                v0 += b2f(rv.x); v1 += b2f(rv.y); v2 += b2f(rv.z); v3 += b2f(rv.w);
            }
            ushort4 st;
            st.x = f2b(fmaxf(v0, 0.f)); st.y = f2b(fmaxf(v1, 0.f));
            st.z = f2b(fmaxf(v2, 0.f)); st.w = f2b(fmaxf(v3, 0.f));
            *(ushort4*)&out[o] = st;
        }
    }
}

// ---------------------------------------------------------------------------
// head: GAP(8x8) + linear 512->200.
// ---------------------------------------------------------------------------
__global__ __launch_bounds__(256)
void head_kernel(const u16* __restrict__ z, const float* __restrict__ hw,
                 float* __restrict__ pred)
{
    const int b = blockIdx.x, tid = threadIdx.x;
    __shared__ float feat[512];
    float s0 = 0.f, s1 = 0.f;
    for (int px = 0; px < 64; ++px){
        u32 u = *(const u32*)&z[(((size_t)b*64 + px)*512) + 2*tid];
        s0 += b2f((u16)(u & 0xFFFF));
        s1 += b2f((u16)(u >> 16));
    }
    feat[2*tid]   = s0 * (1.f/64.f);
    feat[2*tid+1] = s1 * (1.f/64.f);
    __syncthreads();
    if (tid < 200){
        float acc = 0.f;
        const float4* hp = (const float4*)&hw[(size_t)tid*512];
        #pragma unroll 8
        for (int i = 0; i < 128; ++i){
            float4 h = hp[i];
            float4 f = *(const float4*)&feat[i*4];
            acc += h.x*f.x + h.y*f.y + h.z*f.z + h.w*f.w;
        }
        pred[b*200 + tid] = acc;
    }
}

// ---------------------------------------------------------------------------
// gram: fused embed (emb LDS-resident) + Gram + sigmoid; setprio(1).
// ---------------------------------------------------------------------------
__global__ __launch_bounds__(512, 2)
void gram_kernel(const float* __restrict__ x, const u16* __restrict__ wpe,
                 const float* __restrict__ eb, float* __restrict__ vol)
{
    const int b = blockIdx.x, tid = threadIdx.x;
    const int wid = tid >> 6, lane = tid & 63;
    const int ln = lane & 15, kg = lane >> 4;

    __shared__ u16 embl[256*136];        // 69,632 B
    __shared__ u16 xbl[256*40];          // 20,480 B
    __shared__ u16 ewl[128*40];          // 10,240 B

    f32x4 zero4 = {0.f,0.f,0.f,0.f};
    f32x4 ae[8][2];
    #pragma unroll
    for (int mf = 0; mf < 8; ++mf){ ae[mf][0] = zero4; ae[mf][1] = zero4; }

    for (int cc = 0; cc < 8; ++cc){
        __syncthreads();
        #pragma unroll
        for (int it = 0; it < 8; ++it){
            int f = it*512 + tid;
            int cip = f >> 8, px = f & 255;
            const float* src = &x[(((size_t)b*256 + cc*32 + 2*cip)*256) + px];
            *(u32*)&xbl[px*40 + 2*cip] = pack2(src[0], src[256]);
        }
        for (int j = tid; j < 640; j += 512)
            *(short8*)&ewl[j*8] = *(const short8*)&wpe[(cc*128)*40 + j*8];
        __syncthreads();
        short8 A[8];
        #pragma unroll
        for (int mf = 0; mf < 8; ++mf)
            A[mf] = *(const short8*)&ewl[(mf*16 + ln)*40 + kg*8];
        __builtin_amdgcn_s_setprio(1);
        #pragma unroll
        for (int nf = 0; nf < 2; ++nf){
            short8 B = *(const short8*)&xbl[(wid*32 + nf*16 + ln)*40 + kg*8];
            #pragma unroll
            for (int mf = 0; mf < 8; ++mf)
                ae[mf][nf] = MFMA(A[mf], B, ae[mf][nf]);
        }
        __builtin_amdgcn_s_setprio(0);
    }
    #pragma unroll
    for (int mf = 0; mf < 8; ++mf){
        int e0 = mf*16 + kg*4;
        float4 bv = *(const float4*)&eb[e0];
        #pragma unroll
        for (int nf = 0; nf < 2; ++nf){
            int px = wid*32 + nf*16 + ln;
            f32x4 a = ae[mf][nf];
            ushort4 st;
            st.x = f2b(a[0] + bv.x); st.y = f2b(a[1] + bv.y);
            st.z = f2b(a[2] + bv.z); st.w = f2b(a[3] + bv.w);
            *(ushort4*)&embl[px*136 + e0] = st;
        }
    }
    __syncthreads();

    const int wq = wid >> 2, wi = wid & 3;
    f32x4 g[8][4];
    #pragma unroll
    for (int mf = 0; mf < 8; ++mf)
        #pragma unroll
        for (int nf = 0; nf < 4; ++nf) g[mf][nf] = zero4;

    #pragma unroll
    for (int ks = 0; ks < 4; ++ks){
        short8 A[8];
        #pragma unroll
        for (int mf = 0; mf < 8; ++mf)
            A[mf] = *(const short8*)&embl[(wq*128 + mf*16 + ln)*136 + ks*32 + kg*8];
        __builtin_amdgcn_s_setprio(1);
        #pragma unroll
        for (int nf = 0; nf < 4; ++nf){
            short8 B = *(const short8*)&embl[(wi*64 + nf*16 + ln)*136 + ks*32 + kg*8];
            #pragma unroll
            for (int mf = 0; mf < 8; ++mf)
                g[mf][nf] = MFMA(A[mf], B, g[mf][nf]);
        }
        __builtin_amdgcn_s_setprio(0);
    }
    const float sc = 0.08838834764831845f;   // 1/sqrt(128)
    #pragma unroll
    for (int mf = 0; mf < 8; ++mf){
        #pragma unroll
        for (int nf = 0; nf < 4; ++nf){
            int i = wi*64 + nf*16 + ln;
            #pragma unroll
            for (int r = 0; r < 4; ++r){
                int q = wq*128 + mf*16 + kg*4 + r;
                vol[(((size_t)b*256 + q)*256) + i] = sigmoidf_(g[mf][nf][r] * sc);
            }
        }
    }
}

// ---------------------------------------------------------------------------
extern "C" void kernel_launch(void* const* d_in, const int* in_sizes, int n_in,
                              void* d_out, int out_size, void* d_ws, size_t ws_size,
                              hipStream_t stream)
{
    const float* x    = (const float*)d_in[0];
    const float* ew   = (const float*)d_in[1];
    const float* eb   = (const float*)d_in[2];
    const float* w1   = (const float*)d_in[3];
    const float* bn1s = (const float*)d_in[4];
    const float* bn1b = (const float*)d_in[5];
    const float* w2   = (const float*)d_in[6];
    const float* bn2s = (const float*)d_in[7];
    const float* bn2b = (const float*)d_in[8];
    const float* wd   = (const float*)d_in[9];
    const float* bnds = (const float*)d_in[10];
    const float* bndb = (const float*)d_in[11];
    const float* w3   = (const float*)d_in[12];
    const float* bn3s = (const float*)d_in[13];
    const float* bn3b = (const float*)d_in[14];
    const float* w4   = (const float*)d_in[15];
    const float* bn4s = (const float*)d_in[16];
    const float* bn4b = (const float*)d_in[17];
    const float* hw   = (const float*)d_in[18];

    float* pred = (float*)d_out;            // [256,200]
    float* vol  = pred + 51200;             // [256,256,256] f32

    u16* wp2 = (u16*)d_ws;
    u16* wp3 = wp2 + 2949120;
    u16* wp4 = wp3 + 2949120;
    u16* wp1 = wp4 + 2949120;
    u16* wpd = wp1 + 1474560;
    u16* wpe = wpd + 163840;

    u16* y1 = (u16*)vol;
    u16* y  = y1 + 8388608;
    u16* z1 = y  + 8388608;
    u16* z  = z1 + 8388608;

    prep_kernel<<<41120, 256, 0, stream>>>(w1, bn1s, w2, bn2s, w3, bn3s, w4, bn4s,
                                           wd, bnds, ew, wp1, wp2, wp3, wp4, wpd, wpe);
    conv1_kernel<<<dim3(128,2), 512, 0, stream>>>(x, wp1, bn1b, y1);
    conv_s1_kernel<1,0><<<2048, 64, 0, stream>>>(y1, wp2, bn2b, x, wpd, bndb,
                                                 nullptr, y);
    conv_s1_kernel<0,0><<<2048, 64, 0, stream>>>(y, wp3, bn3b, nullptr, nullptr,
                                                 nullptr, nullptr, z1);
    conv_s1_kernel<0,1><<<2048, 64, 0, stream>>>(z1, wp4, bn4b, nullptr, nullptr,
                                                 nullptr, y, z);
    head_kernel<<<256, 256, 0, stream>>>(z, hw, pred);
    gram_kernel<<<256, 512, 0, stream>>>(x, wpe, eb, vol);
}